// Round 4
// baseline (73.400 us; speedup 1.0000x reference)
//
#include <hip/hip_runtime.h>

// KaolinRenderer: coverage-mask rasterizer.
// Output = repeat(mask[B,H,W], 3) — the reference z-buffer is dead code.
//
// BIT-EXACTNESS IS CRITICAL: mask is binary, threshold 2e-2. Faces with
// w-clamped vertices (|ndc| ~1e8) have catastrophically-cancelling edge
// functions whose sign is rounding-determined. We mirror the numpy reference's
// float32 op order exactly and disable FMA contraction for every value that
// feeds the exact inside-test. Skipping faces once a pixel is covered is safe
// (sticky OR); changing per-face exact-test arithmetic is not.
//
// R10: R9 resubmit with the 64-bit shared atomicOr + volatile-u64 read
// replaced by per-wave NON-ATOMIC u64 slots (single writer per slot, volatile
// ds accesses). The R9 bench died at container level (infra or kernel abort);
// the shared u64 atomic was the only novel at-risk construct. Slot scheme is
// race-free by construction: each wave's published ballot is monotone (covered
// is sticky), so stale/torn reads are subsets of the final mask — they can
// only delay early-exit, never corrupt. A wave breaks only when the fold of
// all slots is all-ones (=> result all-ones regardless); with no break, each
// wave's last publish is its full-range ballot => final OR == serial OR.
//
// R9 theory (unchanged, being tested): R7 (broadcast latency) and R8 (cull
// cost, block count) were both neutral at ~63 µs => the wall clock is ONE
// wave's serial survivor loop (a never-covered tile scans all 4096 faces,
// ~33 issue slots per survivor). Fix: 512-thread block per 8x8 tile; all 8
// waves own the SAME 64 pixels; wave w scans face-groups g = w, w+8, ...
// (round-robin keeps the early-exit face order). Critical path /8.
// R8: cull data (A,B,C,err) hoisted to face_pack; midpoint-spread cull
// (FMA allowed in cull only; err has ~2^8 slack); survivor eval uses stored
// A=dx, B=-dy: e = A*(py-ya) + B*(px-xa) is IEEE-identical to reference
// dx*(py-ya) - dy*(px-xa) ((-a)*b == -(a*b), x+(-w) == x-w).
// R6/R7: register cull + ballot compaction; readlane broadcast (k from
// __ballot is wave-uniform -> scalar file, no LDS-pipe ops).

#pragma clang fp contract(off)

#define HW      256
#define BATCH   2
#define VCOUNT  4096
#define FCOUNT  4096
#define WAVES   8
#define CULL_EPS 1.52587890625e-05f   // 2^-16

__global__ __launch_bounds__(256)
void face_pack_kernel(const float* __restrict__ verts,
                      const int* __restrict__ faces,
                      const float* __restrict__ R,
                      const float* __restrict__ T,
                      float4* __restrict__ fxy4,   // [B*F] (x0,y0,x1,y1)
                      float2* __restrict__ fxy2,   // [B*F] (x2,y2)
                      float4* __restrict__ ed0,    // [B*F] (A,B,C,err) edge0
                      float4* __restrict__ ed1,    // [B*F] edge1
                      float4* __restrict__ ed2)    // [B*F] edge2
{
#pragma clang fp contract(off)
    int gid = blockIdx.x * blockDim.x + threadIdx.x;
    if (gid >= BATCH * FCOUNT) return;
    int b = gid / FCOUNT;

    const float fproj = 1.7320508075688772f;   // 1/tan(30deg), f64->f32 like numpy

    const float* Rb = R + b * 9;
    const float* Tb = T + b * 3;

    // t_i = -((Rt[i][0]*T0 + Rt[i][1]*T1) + Rt[i][2]*T2), Rt[i][j] = R[j][i]
    float t0 = -((Rb[0*3+0]*Tb[0] + Rb[1*3+0]*Tb[1]) + Rb[2*3+0]*Tb[2]);
    float t1 = -((Rb[0*3+1]*Tb[0] + Rb[1*3+1]*Tb[1]) + Rb[2*3+1]*Tb[2]);
    float t2 = -((Rb[0*3+2]*Tb[0] + Rb[1*3+2]*Tb[1]) + Rb[2*3+2]*Tb[2]);

    // VP rows 0 (x), 1 (y), 3 (w) only.
    float VP00 = fproj * Rb[0*3+0], VP01 = fproj * Rb[1*3+0],
          VP02 = fproj * Rb[2*3+0], VP03 = fproj * t0;
    float VP10 = fproj * Rb[0*3+1], VP11 = fproj * Rb[1*3+1],
          VP12 = fproj * Rb[2*3+1], VP13 = fproj * t1;
    float VP30 = -Rb[0*3+2], VP31 = -Rb[1*3+2],
          VP32 = -Rb[2*3+2], VP33 = -t2;

    const int* fp = faces + (size_t)gid * 3;
    float xs[3], ys[3];
#pragma unroll
    for (int j = 0; j < 3; ++j) {
        const float* vv = verts + ((size_t)b * VCOUNT + fp[j]) * 3;
        float vx = vv[0], vy = vv[1], vz = vv[2];
        // Identical op sequence to the reference einsum (sequential adds),
        // contract off => bit-identical NDC for every reference to a vertex.
        float cx = ((vx*VP00 + vy*VP01) + vz*VP02) + VP03;
        float cy = ((vx*VP10 + vy*VP11) + vz*VP12) + VP13;
        float cw = ((vx*VP30 + vy*VP31) + vz*VP32) + VP33;
        float w = fmaxf(cw, 1e-8f);
        xs[j] = cx / w;
        ys[j] = cy / w;
    }

    fxy4[gid] = make_float4(xs[0], ys[0], xs[1], ys[1]);
    fxy2[gid] = make_float2(xs[2], ys[2]);

    // Diffs: same f32 ops as the reference's (x1-x0) etc.
    float d01x = xs[1] - xs[0], d01y = ys[1] - ys[0];
    float d12x = xs[2] - xs[1], d12y = ys[2] - ys[1];
    float d20x = xs[0] - xs[2], d20y = ys[0] - ys[2];

    // Per-edge linear model of the reference edge function:
    //   e ~= A*py + B*px + C,  A = dx, B = -dy, C = dy*xa - dx*ya
    // err bounds |model - reference_e| over [-1,1]^2 incl. reference rounding
    // (R4-validated formula, unchanged).
    float C0 = d01y * xs[0] - d01x * ys[0];
    float C1 = d12y * xs[1] - d12x * ys[1];
    float C2 = d20y * xs[2] - d20x * ys[2];
    float e0r = CULL_EPS * (fabsf(d01x) * (1.0f + fabsf(ys[0]))
                          + fabsf(d01y) * (1.0f + fabsf(xs[0])));
    float e1r = CULL_EPS * (fabsf(d12x) * (1.0f + fabsf(ys[1]))
                          + fabsf(d12y) * (1.0f + fabsf(xs[1])));
    float e2r = CULL_EPS * (fabsf(d20x) * (1.0f + fabsf(ys[2]))
                          + fabsf(d20y) * (1.0f + fabsf(xs[2])));

    ed0[gid] = make_float4(d01x, -d01y, C0, e0r);
    ed1[gid] = make_float4(d12x, -d12y, C1, e1r);
    ed2[gid] = make_float4(d20x, -d20y, C2, e2r);
}

// Wave-uniform broadcast through the scalar file (v_readlane_b32).
__device__ __forceinline__ float bcast_lane(float v, int k) {
    return __int_as_float(__builtin_amdgcn_readlane(__float_as_int(v), k));
}

__global__ __launch_bounds__(64 * WAVES)
void raster_kernel(const float4* __restrict__ ed0,
                   const float4* __restrict__ ed1,
                   const float4* __restrict__ ed2,
                   const float4* __restrict__ fxy4,
                   const float2* __restrict__ fxy2,
                   float* __restrict__ out)
{
#pragma clang fp contract(off)
    int b    = blockIdx.y;
    int tile = blockIdx.x;                 // 32x32 tiles of 8x8 over 256x256
    int qx = (tile & 31) << 3;
    int qy = (tile >> 5) << 3;
    int wave = threadIdx.x >> 6;
    int lane = threadIdx.x & 63;
    // ALL waves own the SAME 8x8 pixel rect; they split the face range.
    int px_i = qx + (lane & 7);
    int py_i = qy + (lane >> 3);

    // Same formula as reference: ((i + 0.5)/W)*2 - 1
    float px = (((float)px_i + 0.5f) / 256.0f) * 2.0f - 1.0f;
    float py = (((float)py_i + 0.5f) / 256.0f) * 2.0f - 1.0f;

    // The 8x8 rect (pixel formula is monotone in index).
    float pxlo = (((float)qx       + 0.5f) / 256.0f) * 2.0f - 1.0f;
    float pxhi = (((float)(qx + 7) + 0.5f) / 256.0f) * 2.0f - 1.0f;
    float pylo = (((float)qy       + 0.5f) / 256.0f) * 2.0f - 1.0f;
    float pyhi = (((float)(qy + 7) + 0.5f) / 256.0f) * 2.0f - 1.0f;
    // Midpoint/half-extent form: for linear f = A*py+B*px+C,
    // max/min over rect = base +/- (|A|*yr + |B|*xr). Cull-only arithmetic.
    float xm = 0.5f * (pxlo + pxhi), xr = 0.5f * (pxhi - pxlo);
    float ym = 0.5f * (pylo + pyhi), yr = 0.5f * (pyhi - pylo);

    const float4* e0p = ed0  + (size_t)b * FCOUNT;
    const float4* e1p = ed1  + (size_t)b * FCOUNT;
    const float4* e2p = ed2  + (size_t)b * FCOUNT;
    const float4* f4  = fxy4 + (size_t)b * FCOUNT;
    const float2* f2  = fxy2 + (size_t)b * FCOUNT;

    // Per-wave coverage slots: wmask[w] is written ONLY by wave w's lane 0.
    // Values are monotone (sticky coverage) => cross-wave reads are always
    // valid subsets of the final mask; no atomics needed.
    __shared__ unsigned long long wmask[WAVES];
    if (threadIdx.x < WAVES) wmask[threadIdx.x] = 0ull;
    __syncthreads();
    volatile unsigned long long* vm = wmask;

    bool covered = false;

    // Round-robin group split preserves the serial early-exit face order.
    for (int g = wave; g < FCOUNT / 64; g += WAVES) {
        int idx = (g << 6) + lane;
        float4 E0 = e0p[idx];
        float4 E1 = e1p[idx];
        float4 E2 = e2p[idx];
        float4 q0 = f4[idx];
        float2 q1 = f2[idx];

        // Conservative cull. Skippable iff some edge certifies e<0 over the
        // whole rect AND some edge certifies e>0 (kills both sign branches of
        // `inside`). FMA allowed here: it only tightens the cull's own
        // rounding, and err has ~2^8 slack over f32 eps by construction.
        bool killneg = false, killpos = false;
        {
#pragma clang fp contract(fast)
            float b0 = E0.x * ym + E0.y * xm + E0.z;
            float s0 = fabsf(E0.x) * yr + fabsf(E0.y) * xr;
            killneg = killneg || (b0 + s0 < -E0.w);
            killpos = killpos || (b0 - s0 >  E0.w);
            float b1 = E1.x * ym + E1.y * xm + E1.z;
            float s1 = fabsf(E1.x) * yr + fabsf(E1.y) * xr;
            killneg = killneg || (b1 + s1 < -E1.w);
            killpos = killpos || (b1 - s1 >  E1.w);
            float b2 = E2.x * ym + E2.y * xm + E2.z;
            float s2 = fabsf(E2.x) * yr + fabsf(E2.y) * xr;
            killneg = killneg || (b2 + s2 < -E2.w);
            killpos = killpos || (b2 - s2 >  E2.w);
        }
        bool skip = killneg && killpos;

        // Survivor loop: broadcast lane-k values via v_readlane (k is
        // wave-uniform). No memory ops, no per-survivor ballot check.
        unsigned long long m = __ballot((int)!skip);
        while (m) {
            int k = __ffsll((long long)m) - 1;
            m &= m - 1;
            float A0 = bcast_lane(E0.x, k), B0 = bcast_lane(E0.y, k);
            float A1 = bcast_lane(E1.x, k), B1 = bcast_lane(E1.y, k);
            float A2 = bcast_lane(E2.x, k), B2 = bcast_lane(E2.y, k);
            float ax0 = bcast_lane(q0.x, k), ay0 = bcast_lane(q0.y, k);
            float ax1 = bcast_lane(q0.z, k), ay1 = bcast_lane(q0.w, k);
            float ax2 = bcast_lane(q1.x, k), ay2 = bcast_lane(q1.y, k);
            // e = A*(py-ya) + B*(px-xa), A=dx, B=-dy: bit-identical to the
            // reference dx*(py-ya) - dy*(px-xa) since (-a)*b == -(a*b) and
            // x+(-w) == x-w in IEEE f32. Contract off => no FMA.
            float e0 = A0 * (py - ay0) + B0 * (px - ax0);
            float e1 = A1 * (py - ay1) + B1 * (px - ax1);
            float e2 = A2 * (py - ay2) + B2 * (px - ax2);
            float mn = fminf(fminf(e0, e1), e2);
            float mx = fmaxf(fmaxf(e0, e1), e2);
            covered = covered || (mn >= 0.0f) || (mx <= 0.0f);
        }

        // Publish this wave's coverage, fold in everyone else's, maybe exit.
        unsigned long long bal = __ballot((int)covered);
        if (lane == 0) vm[wave] = bal;
        unsigned long long cur = 0ull;
#pragma unroll
        for (int w2 = 0; w2 < WAVES; ++w2) cur |= vm[w2];
        covered = covered || (((cur >> lane) & 1ull) != 0ull);
        if (__all((int)covered)) break;
    }

    // Final combine. A wave only breaks when the fold of all slots is
    // all-ones (=> result all-ones); otherwise its last in-loop publish is
    // its full-range ballot => OR of slots == serial OR over all faces.
    __syncthreads();

    if (wave == 0) {
        unsigned long long fin = 0ull;
#pragma unroll
        for (int w2 = 0; w2 < WAVES; ++w2) fin |= wmask[w2];
        float val = (((fin >> lane) & 1ull) != 0ull) ? 1.0f : 0.0f;
        size_t o = ((size_t)(b * HW + py_i) * HW + px_i) * 3;
        out[o + 0] = val;
        out[o + 1] = val;
        out[o + 2] = val;
    }
}

extern "C" void kernel_launch(void* const* d_in, const int* in_sizes, int n_in,
                              void* d_out, int out_size, void* d_ws, size_t ws_size,
                              hipStream_t stream) {
    const float* verts = (const float*)d_in[0];   // [2,4096,3] f32
    const int*   faces = (const int*)d_in[1];     // [2,4096,3] i32
    const float* R     = (const float*)d_in[2];   // [2,3,3]    f32
    const float* T     = (const float*)d_in[3];   // [2,3]      f32
    float*       out   = (float*)d_out;           // [2,256,256,3] f32

    float4* fxy4 = (float4*)d_ws;                        // 128 KiB
    float2* fxy2 = (float2*)(fxy4 + BATCH * FCOUNT);     // 64 KiB
    float4* ed0  = (float4*)(fxy2 + BATCH * FCOUNT);     // 128 KiB
    float4* ed1  = ed0 + BATCH * FCOUNT;                 // 128 KiB
    float4* ed2  = ed1 + BATCH * FCOUNT;                 // 128 KiB

    int nf = BATCH * FCOUNT;
    face_pack_kernel<<<(nf + 255) / 256, 256, 0, stream>>>(verts, faces, R, T,
                                                           fxy4, fxy2,
                                                           ed0, ed1, ed2);

    dim3 grid(32 * 32, BATCH);
    raster_kernel<<<grid, 64 * WAVES, 0, stream>>>(ed0, ed1, ed2, fxy4, fxy2, out);
}

// Round 5
// 69.033 us; speedup vs baseline: 1.0633x; 1.0633x over previous
//
#include <hip/hip_runtime.h>

// KaolinRenderer: coverage-mask rasterizer.
// Output = repeat(mask[B,H,W], 3) — the reference z-buffer is dead code.
//
// BIT-EXACTNESS IS CRITICAL: mask is binary, threshold 2e-2. Faces with
// w-clamped vertices (|ndc| ~1e8) have catastrophically-cancelling edge
// functions whose sign is rounding-determined. We mirror the numpy reference's
// float32 op order exactly and disable FMA contraction for every value that
// feeds the exact inside-test. Skipping faces once a pixel is covered is safe
// (sticky OR); changing per-face exact-test arithmetic is not.
//
// R11: SINGLE fused kernel, ZERO workspace use. Diagnosis: every top-5
// rocprof dispatch is fillBufferAligned writing 256 MiB (= the workspace)
// at ~40 µs per iteration — the harness re-poisons d_ws INSIDE the timed
// region. Our raster never shows in top-5 (=> < 40 µs). The 63 µs plateau
// that was invariant under R7 (readlane), R8 (hoisted cull, 2048 blocks)
// micro-opts is plausibly fill(40) + pack(3) + raster(20); R10's +10 µs
// regression (8-way scan split => ~8x cull work on covered tiles) shows the
// raster term tracks aggregate work. Eliminating all d_ws use tests the
// poison hypothesis and wins under both decompositions (removes the fill
// if poison is conditional; removes a launch gap otherwise).
//
// Structure: one block (512 thr, 8 waves) per 8 tiles; block cooperatively
// transforms ALL 4096 faces of its batch into LDS (float4+float2 = 96 KiB,
// naturally aligned for ds_read_b128/b64), one barrier, then each wave
// rasterizes its OWN 8x8 tile from LDS (R8's per-wave-tile structure).
// NOT R5's failed fusion: transform is a wide parallel prologue (8 faces/
// thread, gathers overlapped), not a dependent chain inside the scan.
// Redundant transform cost: 128 blocks/batch x 4096 faces ~ 1.3 µs aggregate.
// 256 blocks = 1/CU (96 KiB LDS), 8 waves = 2/SIMD — same occupancy as R8.
//
// Numerics per phase (all previously validated, unchanged):
//  - Transform: face_pack's exact op sequence (sequential adds, contract
//    off, IEEE divide) => bit-identical NDC per vertex reference.
//  - Cull: R7's corner-select conservative half-plane test with the
//    R4-validated err bound (CULL_EPS = 2^-16 covers linear-model +
//    reference rounding over [-1,1]^2). Kills a face only if some edge
//    certifies e<0 rect-wide AND some edge certifies e>0 rect-wide.
//  - Survivor eval: broadcast lane-k coords via v_readlane (k wave-uniform
//    from __ballot => scalar file); diffs recomputed per-lane with the
//    reference's exact f32 ops; e = dx*(py-y0) - dy*(px-x0), contract off.

#pragma clang fp contract(off)

#define HW      256
#define BATCH   2
#define VCOUNT  4096
#define FCOUNT  4096
#define WAVES   8
#define CULL_EPS 1.52587890625e-05f   // 2^-16

// Wave-uniform broadcast through the scalar file (v_readlane_b32).
__device__ __forceinline__ float bcast_lane(float v, int k) {
    return __int_as_float(__builtin_amdgcn_readlane(__float_as_int(v), k));
}

__global__ __launch_bounds__(64 * WAVES)
void render_kernel(const float* __restrict__ verts,
                   const int* __restrict__ faces,
                   const float* __restrict__ R,
                   const float* __restrict__ T,
                   float* __restrict__ out)
{
#pragma clang fp contract(off)
    // Per-face NDC xy cache: naturally aligned for ds_read_b128 / ds_read_b64.
    __shared__ float4 sA[FCOUNT];   // (x0,y0,x1,y1)  64 KiB
    __shared__ float2 sB[FCOUNT];   // (x2,y2)        32 KiB

    int b   = blockIdx.y;
    int tid = threadIdx.x;

    // ---- Phase 0: camera matrix (per-thread; ~30 ops, amortized over 8 faces)
    const float fproj = 1.7320508075688772f;   // 1/tan(30deg), f64->f32 like numpy
    const float* Rb = R + b * 9;
    const float* Tb = T + b * 3;

    // t_i = -((Rt[i][0]*T0 + Rt[i][1]*T1) + Rt[i][2]*T2), Rt[i][j] = R[j][i]
    float t0 = -((Rb[0*3+0]*Tb[0] + Rb[1*3+0]*Tb[1]) + Rb[2*3+0]*Tb[2]);
    float t1 = -((Rb[0*3+1]*Tb[0] + Rb[1*3+1]*Tb[1]) + Rb[2*3+1]*Tb[2]);
    float t2 = -((Rb[0*3+2]*Tb[0] + Rb[1*3+2]*Tb[1]) + Rb[2*3+2]*Tb[2]);

    // VP rows 0 (x), 1 (y), 3 (w) only.
    float VP00 = fproj * Rb[0*3+0], VP01 = fproj * Rb[1*3+0],
          VP02 = fproj * Rb[2*3+0], VP03 = fproj * t0;
    float VP10 = fproj * Rb[0*3+1], VP11 = fproj * Rb[1*3+1],
          VP12 = fproj * Rb[2*3+1], VP13 = fproj * t1;
    float VP30 = -Rb[0*3+2], VP31 = -Rb[1*3+2],
          VP32 = -Rb[2*3+2], VP33 = -t2;

    // ---- Phase 1: cooperative face transform into LDS (8 faces/thread).
    for (int f = tid; f < FCOUNT; f += 64 * WAVES) {
        const int* fp = faces + ((size_t)b * FCOUNT + f) * 3;
        float xs[3], ys[3];
#pragma unroll
        for (int j = 0; j < 3; ++j) {
            const float* vv = verts + ((size_t)b * VCOUNT + fp[j]) * 3;
            float vx = vv[0], vy = vv[1], vz = vv[2];
            // Identical op sequence to the reference einsum (sequential adds),
            // contract off => bit-identical NDC for every reference to a vertex.
            float cx = ((vx*VP00 + vy*VP01) + vz*VP02) + VP03;
            float cy = ((vx*VP10 + vy*VP11) + vz*VP12) + VP13;
            float cw = ((vx*VP30 + vy*VP31) + vz*VP32) + VP33;
            float w = fmaxf(cw, 1e-8f);
            xs[j] = cx / w;           // IEEE f32 divide, same as reference
            ys[j] = cy / w;
        }
        sA[f] = make_float4(xs[0], ys[0], xs[1], ys[1]);
        sB[f] = make_float2(xs[2], ys[2]);
    }
    __syncthreads();   // all threads reach this unconditionally

    // ---- Phase 2: each wave rasterizes its own 8x8 tile from LDS.
    int wave = tid >> 6;
    int lane = tid & 63;
    int tile = blockIdx.x * WAVES + wave;   // [0,1024): 32x32 tiles of 8x8
    int qx = (tile & 31) << 3;
    int qy = (tile >> 5) << 3;
    int px_i = qx + (lane & 7);
    int py_i = qy + (lane >> 3);

    // Same formula as reference: ((i + 0.5)/W)*2 - 1
    float px = (((float)px_i + 0.5f) / 256.0f) * 2.0f - 1.0f;
    float py = (((float)py_i + 0.5f) / 256.0f) * 2.0f - 1.0f;

    // The wave's 8x8 rect (pixel formula is monotone in index).
    float pxlo = (((float)qx       + 0.5f) / 256.0f) * 2.0f - 1.0f;
    float pxhi = (((float)(qx + 7) + 0.5f) / 256.0f) * 2.0f - 1.0f;
    float pylo = (((float)qy       + 0.5f) / 256.0f) * 2.0f - 1.0f;
    float pyhi = (((float)(qy + 7) + 0.5f) / 256.0f) * 2.0f - 1.0f;

    bool covered = false;

    for (int g = 0; g < FCOUNT; g += 64) {
        if (__all((int)covered)) break;

        // Lane owns face g+lane straight from LDS (b128 + b64, aligned).
        float4 q0 = sA[g + lane];
        float2 q1 = sB[g + lane];
        float x0 = q0.x, y0 = q0.y, x1 = q0.z, y1 = q0.w;
        float x2 = q1.x, y2 = q1.y;
        // Diffs: same f32 ops as the reference's (x1-x0) etc.
        float d01x = x1 - x0, d01y = y1 - y0;
        float d12x = x2 - x1, d12y = y2 - y1;
        float d20x = x0 - x2, d20y = y0 - y2;

        // Conservative cull (R7/R4-validated): e(p) ~= A*py + B*px + C over
        // the rect. Skippable iff some edge certifies e<0 everywhere AND some
        // edge certifies e>0 everywhere (kills both sign branches of `inside`).
        bool killneg = false, killpos = false;
        {
            float A[3]  = { d01x, d12x, d20x };
            float Bc[3] = { -d01y, -d12y, -d20y };
            float xa[3] = { x0, x1, x2 };
            float ya[3] = { y0, y1, y2 };
#pragma unroll
            for (int e = 0; e < 3; ++e) {
                float C = (-Bc[e]) * xa[e] - A[e] * ya[e];
                float err = CULL_EPS * (fabsf(A[e])  * (1.0f + fabsf(ya[e]))
                                      + fabsf(Bc[e]) * (1.0f + fabsf(xa[e])));
                float yh = (A[e]  > 0.0f) ? pyhi : pylo;
                float yl = (A[e]  > 0.0f) ? pylo : pyhi;
                float xh = (Bc[e] > 0.0f) ? pxhi : pxlo;
                float xl = (Bc[e] > 0.0f) ? pxlo : pxhi;
                float hi = A[e] * yh + Bc[e] * xh + C;
                float lo = A[e] * yl + Bc[e] * xl + C;
                killneg = killneg || (hi < -err);
                killpos = killpos || (lo >  err);
            }
        }
        bool skip = killneg && killpos;

        // Survivor loop: broadcast lane-k values via v_readlane (k is
        // wave-uniform). No memory ops inside.
        unsigned long long m = __ballot((int)!skip);
        while (m) {
            int k = __ffsll((long long)m) - 1;
            m &= m - 1;
            float bx0 = bcast_lane(x0, k), by0 = bcast_lane(y0, k);
            float bx1 = bcast_lane(x1, k), by1 = bcast_lane(y1, k);
            float bx2 = bcast_lane(x2, k), by2 = bcast_lane(y2, k);
            // Recomputed diffs: identical f32 operands+op as reference.
            float bd01x = bx1 - bx0, bd01y = by1 - by0;
            float bd12x = bx2 - bx1, bd12y = by2 - by1;
            float bd20x = bx0 - bx2, bd20y = by0 - by2;
            // e = (x1-x0)*(py-y0) - (y1-y0)*(px-x0): mul, mul, sub — no FMA
            float e0 = bd01x * (py - by0) - bd01y * (px - bx0);
            float e1 = bd12x * (py - by1) - bd12y * (px - bx1);
            float e2 = bd20x * (py - by2) - bd20y * (px - bx2);
            float mn = fminf(fminf(e0, e1), e2);
            float mx = fmaxf(fmaxf(e0, e1), e2);
            covered = covered || (mn >= 0.0f) || (mx <= 0.0f);
        }
    }

    float val = covered ? 1.0f : 0.0f;
    size_t o = ((size_t)(b * HW + py_i) * HW + px_i) * 3;
    out[o + 0] = val;
    out[o + 1] = val;
    out[o + 2] = val;
}

extern "C" void kernel_launch(void* const* d_in, const int* in_sizes, int n_in,
                              void* d_out, int out_size, void* d_ws, size_t ws_size,
                              hipStream_t stream) {
    const float* verts = (const float*)d_in[0];   // [2,4096,3] f32
    const int*   faces = (const int*)d_in[1];     // [2,4096,3] i32
    const float* R     = (const float*)d_in[2];   // [2,3,3]    f32
    const float* T     = (const float*)d_in[3];   // [2,3]      f32
    float*       out   = (float*)d_out;           // [2,256,256,3] f32

    (void)d_ws; (void)ws_size;                    // workspace deliberately unused

    // 8 tiles per block (one per wave), 1024 tiles per batch.
    dim3 grid(1024 / WAVES, BATCH);
    render_kernel<<<grid, 64 * WAVES, 0, stream>>>(verts, faces, R, T, out);
}

// Round 6
// 68.960 us; speedup vs baseline: 1.0644x; 1.0011x over previous
//
#include <hip/hip_runtime.h>

// KaolinRenderer: coverage-mask rasterizer.
// Output = repeat(mask[B,H,W], 3) — the reference z-buffer is dead code.
//
// BIT-EXACTNESS IS CRITICAL: mask is binary, threshold 2e-2. Faces with
// w-clamped vertices (|ndc| ~1e8) have catastrophically-cancelling edge
// functions whose sign is rounding-determined. We mirror the numpy reference's
// float32 op order exactly and disable FMA contraction for every value that
// feeds the exact inside-test. Skipping faces once a pixel is covered is safe
// (sticky OR); changing per-face exact-test arithmetic is not.
//
// R12: two-phase tail attack. Model fitting R6-R11: dur ~= fill(40 µs,
// harness poisons 256 MiB ws unconditionally — R11 proved it persists with
// zero ws use) + pack(~3) + raster(X). X is dominated by tail tiles (never
// covered) whose ONE wave serially evaluates ~600 survivors x ~39 slots.
// R10's 8-way split died on covered-tile inflation + serialized volatile-LDS
// folds. Fix here:
//   Phase A: one wave/tile scans ONLY groups 0..7; interior tiles finish in
//     1-2 groups. Partial 64b ballot -> ws masks; unresolved tile ids
//     compacted via global atomicAdd (counter zeroed by face_pack).
//   Phase B: 8 waves per UNRESOLVED tile only (2048 blocks, empties exit on
//     a uniform count load). Waves split groups 8..63 round-robin, no
//     coordination except a per-group uniform "mask full?" load (monotone
//     u32 pair: stale/torn reads are subsets => only delays exit). Each wave
//     ends with two u32 global atomicOrs (no u64/shared atomics — R9 risk).
//     Tail critical path: 7 groups + ~1/8 of survivors (~2.5 µs vs ~20).
//   Phase C: one thread/pixel writes output from the final masks.
// Covered tiles are NOT inflated (B runs only on unresolved tiles).
// All pinned arithmetic (pack, cull + R4-validated err bound, anchored
// survivor eval) is byte-for-byte R8's, which passed with absmax 0.
// R8: cull data (A,B,C,err) hoisted to face_pack; midpoint-spread cull (FMA
// allowed in cull only; err has ~2^8 slack); survivor eval uses stored A=dx,
// B=-dy: e = A*(py-ya) + B*(px-xa) IEEE-identical to reference
// dx*(py-ya) - dy*(px-xa) ((-a)*b == -(a*b), x+(-w) == x-w).
// R6/R7: register cull + ballot compaction; readlane broadcast (k from
// __ballot is wave-uniform -> scalar file).

#pragma clang fp contract(off)

#define HW      256
#define BATCH   2
#define VCOUNT  4096
#define FCOUNT  4096
#define NTILES  1024          // 32x32 tiles of 8x8 per batch
#define GTILES  (BATCH * NTILES)
#define K_CAP   8             // groups scanned in phase A
#define CULL_EPS 1.52587890625e-05f   // 2^-16

__global__ __launch_bounds__(256)
void face_pack_kernel(const float* __restrict__ verts,
                      const int* __restrict__ faces,
                      const float* __restrict__ R,
                      const float* __restrict__ T,
                      float4* __restrict__ fxy4,   // [B*F] (x0,y0,x1,y1)
                      float2* __restrict__ fxy2,   // [B*F] (x2,y2)
                      float4* __restrict__ ed0,    // [B*F] (A,B,C,err) edge0
                      float4* __restrict__ ed1,    // [B*F] edge1
                      float4* __restrict__ ed2,    // [B*F] edge2
                      unsigned* __restrict__ count) // phase-B list counter
{
#pragma clang fp contract(off)
    int gid = blockIdx.x * blockDim.x + threadIdx.x;
    if (gid == 0) *count = 0u;          // stream-ordered before phase A
    if (gid >= BATCH * FCOUNT) return;
    int b = gid / FCOUNT;

    const float fproj = 1.7320508075688772f;   // 1/tan(30deg), f64->f32 like numpy

    const float* Rb = R + b * 9;
    const float* Tb = T + b * 3;

    // t_i = -((Rt[i][0]*T0 + Rt[i][1]*T1) + Rt[i][2]*T2), Rt[i][j] = R[j][i]
    float t0 = -((Rb[0*3+0]*Tb[0] + Rb[1*3+0]*Tb[1]) + Rb[2*3+0]*Tb[2]);
    float t1 = -((Rb[0*3+1]*Tb[0] + Rb[1*3+1]*Tb[1]) + Rb[2*3+1]*Tb[2]);
    float t2 = -((Rb[0*3+2]*Tb[0] + Rb[1*3+2]*Tb[1]) + Rb[2*3+2]*Tb[2]);

    // VP rows 0 (x), 1 (y), 3 (w) only.
    float VP00 = fproj * Rb[0*3+0], VP01 = fproj * Rb[1*3+0],
          VP02 = fproj * Rb[2*3+0], VP03 = fproj * t0;
    float VP10 = fproj * Rb[0*3+1], VP11 = fproj * Rb[1*3+1],
          VP12 = fproj * Rb[2*3+1], VP13 = fproj * t1;
    float VP30 = -Rb[0*3+2], VP31 = -Rb[1*3+2],
          VP32 = -Rb[2*3+2], VP33 = -t2;

    const int* fp = faces + (size_t)gid * 3;
    float xs[3], ys[3];
#pragma unroll
    for (int j = 0; j < 3; ++j) {
        const float* vv = verts + ((size_t)b * VCOUNT + fp[j]) * 3;
        float vx = vv[0], vy = vv[1], vz = vv[2];
        // Identical op sequence to the reference einsum (sequential adds),
        // contract off => bit-identical NDC for every reference to a vertex.
        float cx = ((vx*VP00 + vy*VP01) + vz*VP02) + VP03;
        float cy = ((vx*VP10 + vy*VP11) + vz*VP12) + VP13;
        float cw = ((vx*VP30 + vy*VP31) + vz*VP32) + VP33;
        float w = fmaxf(cw, 1e-8f);
        xs[j] = cx / w;
        ys[j] = cy / w;
    }

    fxy4[gid] = make_float4(xs[0], ys[0], xs[1], ys[1]);
    fxy2[gid] = make_float2(xs[2], ys[2]);

    // Diffs: same f32 ops as the reference's (x1-x0) etc.
    float d01x = xs[1] - xs[0], d01y = ys[1] - ys[0];
    float d12x = xs[2] - xs[1], d12y = ys[2] - ys[1];
    float d20x = xs[0] - xs[2], d20y = ys[0] - ys[2];

    // Per-edge linear model of the reference edge function:
    //   e ~= A*py + B*px + C,  A = dx, B = -dy, C = dy*xa - dx*ya
    // err bounds |model - reference_e| over [-1,1]^2 incl. reference rounding
    // (R4-validated formula, unchanged).
    float C0 = d01y * xs[0] - d01x * ys[0];
    float C1 = d12y * xs[1] - d12x * ys[1];
    float C2 = d20y * xs[2] - d20x * ys[2];
    float e0r = CULL_EPS * (fabsf(d01x) * (1.0f + fabsf(ys[0]))
                          + fabsf(d01y) * (1.0f + fabsf(xs[0])));
    float e1r = CULL_EPS * (fabsf(d12x) * (1.0f + fabsf(ys[1]))
                          + fabsf(d12y) * (1.0f + fabsf(xs[1])));
    float e2r = CULL_EPS * (fabsf(d20x) * (1.0f + fabsf(ys[2]))
                          + fabsf(d20y) * (1.0f + fabsf(xs[2])));

    ed0[gid] = make_float4(d01x, -d01y, C0, e0r);
    ed1[gid] = make_float4(d12x, -d12y, C1, e1r);
    ed2[gid] = make_float4(d20x, -d20y, C2, e2r);
}

// Wave-uniform broadcast through the scalar file (v_readlane_b32).
__device__ __forceinline__ float bcast_lane(float v, int k) {
    return __int_as_float(__builtin_amdgcn_readlane(__float_as_int(v), k));
}

// One 64-face group: conservative cull (validated err bound) + bit-exact
// survivor eval via readlane broadcast. Updates `covered` (sticky OR).
__device__ __forceinline__ void scan_group(
    int idx,
    const float4* __restrict__ e0p, const float4* __restrict__ e1p,
    const float4* __restrict__ e2p, const float4* __restrict__ f4,
    const float2* __restrict__ f2,
    float px, float py, float xm, float xr, float ym, float yr,
    bool& covered)
{
    float4 E0 = e0p[idx];
    float4 E1 = e1p[idx];
    float4 E2 = e2p[idx];
    float4 q0 = f4[idx];
    float2 q1 = f2[idx];

    // Conservative cull. Skippable iff some edge certifies e<0 over the
    // whole rect AND some edge certifies e>0 (kills both sign branches of
    // `inside`). FMA allowed here: it only tightens the cull's own rounding,
    // and err has ~2^8 slack over f32 eps by construction.
    bool killneg = false, killpos = false;
    {
#pragma clang fp contract(fast)
        float b0 = E0.x * ym + E0.y * xm + E0.z;
        float s0 = fabsf(E0.x) * yr + fabsf(E0.y) * xr;
        killneg = killneg || (b0 + s0 < -E0.w);
        killpos = killpos || (b0 - s0 >  E0.w);
        float b1 = E1.x * ym + E1.y * xm + E1.z;
        float s1 = fabsf(E1.x) * yr + fabsf(E1.y) * xr;
        killneg = killneg || (b1 + s1 < -E1.w);
        killpos = killpos || (b1 - s1 >  E1.w);
        float b2 = E2.x * ym + E2.y * xm + E2.z;
        float s2 = fabsf(E2.x) * yr + fabsf(E2.y) * xr;
        killneg = killneg || (b2 + s2 < -E2.w);
        killpos = killpos || (b2 - s2 >  E2.w);
    }
    bool skip = killneg && killpos;

    // Survivor loop: broadcast lane-k values via v_readlane (k is
    // wave-uniform). No memory ops inside.
    unsigned long long m = __ballot((int)!skip);
    while (m) {
        int k = __ffsll((long long)m) - 1;
        m &= m - 1;
        float A0 = bcast_lane(E0.x, k), B0 = bcast_lane(E0.y, k);
        float A1 = bcast_lane(E1.x, k), B1 = bcast_lane(E1.y, k);
        float A2 = bcast_lane(E2.x, k), B2 = bcast_lane(E2.y, k);
        float ax0 = bcast_lane(q0.x, k), ay0 = bcast_lane(q0.y, k);
        float ax1 = bcast_lane(q0.z, k), ay1 = bcast_lane(q0.w, k);
        float ax2 = bcast_lane(q1.x, k), ay2 = bcast_lane(q1.y, k);
        // e = A*(py-ya) + B*(px-xa), A=dx, B=-dy: bit-identical to the
        // reference dx*(py-ya) - dy*(px-xa) since (-a)*b == -(a*b) and
        // x+(-w) == x-w in IEEE f32. Contract off => no FMA.
        float e0 = A0 * (py - ay0) + B0 * (px - ax0);
        float e1 = A1 * (py - ay1) + B1 * (px - ax1);
        float e2 = A2 * (py - ay2) + B2 * (px - ax2);
        float mn = fminf(fminf(e0, e1), e2);
        float mx = fmaxf(fmaxf(e0, e1), e2);
        covered = covered || (mn >= 0.0f) || (mx <= 0.0f);
    }
}

// Phase A: one wave per tile, groups 0..K_CAP-1 only. Writes partial ballot;
// appends unresolved tiles to the compacted list.
__global__ __launch_bounds__(64)
void raster_a(const float4* __restrict__ ed0, const float4* __restrict__ ed1,
              const float4* __restrict__ ed2, const float4* __restrict__ fxy4,
              const float2* __restrict__ fxy2,
              unsigned* __restrict__ masks,    // [GTILES*2] lo,hi
              unsigned* __restrict__ list,     // [GTILES]
              unsigned* __restrict__ count)
{
#pragma clang fp contract(off)
    int b    = blockIdx.y;
    int tile = blockIdx.x;                 // 32x32 tiles of 8x8 over 256x256
    int qx = (tile & 31) << 3;
    int qy = (tile >> 5) << 3;
    int lane = threadIdx.x;
    int px_i = qx + (lane & 7);
    int py_i = qy + (lane >> 3);

    // Same formula as reference: ((i + 0.5)/W)*2 - 1
    float px = (((float)px_i + 0.5f) / 256.0f) * 2.0f - 1.0f;
    float py = (((float)py_i + 0.5f) / 256.0f) * 2.0f - 1.0f;

    float pxlo = (((float)qx       + 0.5f) / 256.0f) * 2.0f - 1.0f;
    float pxhi = (((float)(qx + 7) + 0.5f) / 256.0f) * 2.0f - 1.0f;
    float pylo = (((float)qy       + 0.5f) / 256.0f) * 2.0f - 1.0f;
    float pyhi = (((float)(qy + 7) + 0.5f) / 256.0f) * 2.0f - 1.0f;
    float xm = 0.5f * (pxlo + pxhi), xr = 0.5f * (pxhi - pxlo);
    float ym = 0.5f * (pylo + pyhi), yr = 0.5f * (pyhi - pylo);

    const float4* e0p = ed0  + (size_t)b * FCOUNT;
    const float4* e1p = ed1  + (size_t)b * FCOUNT;
    const float4* e2p = ed2  + (size_t)b * FCOUNT;
    const float4* f4  = fxy4 + (size_t)b * FCOUNT;
    const float2* f2  = fxy2 + (size_t)b * FCOUNT;

    bool covered = false;
    for (int g = 0; g < K_CAP * 64; g += 64) {
        scan_group(g + lane, e0p, e1p, e2p, f4, f2,
                   px, py, xm, xr, ym, yr, covered);
        if (__all((int)covered)) break;
    }

    unsigned long long bal = __ballot((int)covered);
    int gt = b * NTILES + tile;
    bool done = (bal == ~0ull);
    if (lane == 0) {
        masks[2*gt + 0] = (unsigned)bal;
        masks[2*gt + 1] = (unsigned)(bal >> 32);
        if (!done) {
            unsigned idx = atomicAdd(count, 1u);
            list[idx] = (unsigned)gt;
        }
    }
}

// Phase B: 8 waves per unresolved tile, splitting groups K_CAP..63
// round-robin. No inter-wave coordination except a per-group uniform
// "mask full?" load (monotone => stale/torn reads only delay exit).
__global__ __launch_bounds__(512)
void raster_b(const float4* __restrict__ ed0, const float4* __restrict__ ed1,
              const float4* __restrict__ ed2, const float4* __restrict__ fxy4,
              const float2* __restrict__ fxy2,
              unsigned* __restrict__ masks,
              const unsigned* __restrict__ list,
              const unsigned* __restrict__ count)
{
#pragma clang fp contract(off)
    unsigned cnt = *count;
    if (blockIdx.x >= cnt) return;
    int gt   = (int)list[blockIdx.x];
    int b    = gt >> 10;
    int tile = gt & (NTILES - 1);
    int wave = threadIdx.x >> 6;
    int lane = threadIdx.x & 63;

    int qx = (tile & 31) << 3;
    int qy = (tile >> 5) << 3;
    int px_i = qx + (lane & 7);
    int py_i = qy + (lane >> 3);

    float px = (((float)px_i + 0.5f) / 256.0f) * 2.0f - 1.0f;
    float py = (((float)py_i + 0.5f) / 256.0f) * 2.0f - 1.0f;

    float pxlo = (((float)qx       + 0.5f) / 256.0f) * 2.0f - 1.0f;
    float pxhi = (((float)(qx + 7) + 0.5f) / 256.0f) * 2.0f - 1.0f;
    float pylo = (((float)qy       + 0.5f) / 256.0f) * 2.0f - 1.0f;
    float pyhi = (((float)(qy + 7) + 0.5f) / 256.0f) * 2.0f - 1.0f;
    float xm = 0.5f * (pxlo + pxhi), xr = 0.5f * (pxhi - pxlo);
    float ym = 0.5f * (pylo + pyhi), yr = 0.5f * (pyhi - pylo);

    const float4* e0p = ed0  + (size_t)b * FCOUNT;
    const float4* e1p = ed1  + (size_t)b * FCOUNT;
    const float4* e2p = ed2  + (size_t)b * FCOUNT;
    const float4* f4  = fxy4 + (size_t)b * FCOUNT;
    const float2* f2  = fxy2 + (size_t)b * FCOUNT;

    bool covered = false;
    for (int gi = K_CAP + wave; gi < FCOUNT / 64; gi += 8) {
        // Uniform early-out: tile already fully covered (monotone mask).
        unsigned lo = masks[2*gt + 0];
        unsigned hi = masks[2*gt + 1];
        if ((lo & hi) == 0xffffffffu) break;
        scan_group((gi << 6) + lane, e0p, e1p, e2p, f4, f2,
                   px, py, xm, xr, ym, yr, covered);
    }

    unsigned long long bal = __ballot((int)covered);
    if (lane == 0) {
        if ((unsigned)bal)         atomicOr(&masks[2*gt + 0], (unsigned)bal);
        if ((unsigned)(bal >> 32)) atomicOr(&masks[2*gt + 1], (unsigned)(bal >> 32));
    }
}

// Phase C: one thread per pixel, write output from final masks.
__global__ __launch_bounds__(256)
void raster_c(const unsigned* __restrict__ masks, float* __restrict__ out)
{
    int gid = blockIdx.x * 256 + threadIdx.x;      // [0, B*H*W)
    int b = gid >> 16;
    int p = gid & 65535;
    int py = p >> 8, px = p & 255;
    int tile = ((py >> 3) << 5) + (px >> 3);
    int gt = b * NTILES + tile;
    int bit = ((py & 7) << 3) + (px & 7);
    unsigned word = masks[2*gt + (bit >> 5)];
    float val = ((word >> (bit & 31)) & 1u) ? 1.0f : 0.0f;
    size_t o = (size_t)gid * 3;
    out[o + 0] = val;
    out[o + 1] = val;
    out[o + 2] = val;
}

extern "C" void kernel_launch(void* const* d_in, const int* in_sizes, int n_in,
                              void* d_out, int out_size, void* d_ws, size_t ws_size,
                              hipStream_t stream) {
    const float* verts = (const float*)d_in[0];   // [2,4096,3] f32
    const int*   faces = (const int*)d_in[1];     // [2,4096,3] i32
    const float* R     = (const float*)d_in[2];   // [2,3,3]    f32
    const float* T     = (const float*)d_in[3];   // [2,3]      f32
    float*       out   = (float*)d_out;           // [2,256,256,3] f32

    float4* fxy4 = (float4*)d_ws;                        // 128 KiB
    float2* fxy2 = (float2*)(fxy4 + BATCH * FCOUNT);     // 64 KiB
    float4* ed0  = (float4*)(fxy2 + BATCH * FCOUNT);     // 128 KiB
    float4* ed1  = ed0 + BATCH * FCOUNT;                 // 128 KiB
    float4* ed2  = ed1 + BATCH * FCOUNT;                 // 128 KiB
    unsigned* masks = (unsigned*)(ed2 + BATCH * FCOUNT); // 16 KiB
    unsigned* list  = masks + GTILES * 2;                // 8 KiB
    unsigned* count = list + GTILES;                     // 4 B

    int nf = BATCH * FCOUNT;
    face_pack_kernel<<<(nf + 255) / 256, 256, 0, stream>>>(verts, faces, R, T,
                                                           fxy4, fxy2,
                                                           ed0, ed1, ed2, count);

    dim3 gridA(NTILES, BATCH);
    raster_a<<<gridA, 64, 0, stream>>>(ed0, ed1, ed2, fxy4, fxy2,
                                       masks, list, count);

    raster_b<<<GTILES, 512, 0, stream>>>(ed0, ed1, ed2, fxy4, fxy2,
                                         masks, list, count);

    raster_c<<<(BATCH * HW * HW) / 256, 256, 0, stream>>>(masks, out);
}